// Round 12
// baseline (236.693 us; speedup 1.0000x reference)
//
#include <hip/hip_runtime.h>
#include <hip/hip_bf16.h>

typedef unsigned int   u32;
typedef unsigned short u16;
typedef unsigned char  u8;
typedef float f32x2 __attribute__((ext_vector_type(2)));
typedef float f32x4 __attribute__((ext_vector_type(4)));

#define N_NODES 50000
#define C_DIM   128
#define E_EDGES 1600000
#define NUM_IDX 2048

#define CPB 256                    // cols per coarse bucket (key >> 8)
#define NB  196                    // ceil(N/CPB)
#define CAP 9216                   // padded capacity per bucket (mean 8192, sigma ~90)
#define CHK 8192                   // edges per chunk
#define NP  196                    // ceil(E/CHK)
#define PT  512                    // threads for partition-family kernels
#define EPT 16                     // edges per thread in partition (CHK/PT)
#define GB  16                     // nodes per label-matmul block (r11: 8->16)
#define XPAD 20                    // xsT inner stride: rows 16B-aligned, 8-way banks
#define NLB 98                     // label-stripe blocks of 512 (ceil(N/512))

// LESSONS (journal):
// r5: device-scope global atomics on MI355X are HBM-side RMW. Keep hists in LDS.
// r6: f32x4-casting per-g LDS reads in double-unrolled loops -> scratch spill
//     (fix: k-major LDS layout so vector reads are broadcast, accs static-idx).
// r7: node_msg LDS-issue bound; k-major staging (xsT[k][g]) broadcast b128.
// r8: gather one-shot is L3-random bound (149MB @ 2.7TB/s = 54us floor).
// r10: 4-pass channel-split gather REGRESSED: no L2 residency vs streaming
//      co-tenants. 1 wave/block for node_msg (no duplicate broadcasts).
// r11: node_msg is 75% memory-latency stall (VALUBusy 25%) -> GB=16 amortizes
//      W-stream (halves L2 traffic/node) at cost of halved wave count.

// K_A: blocks 0..NP-1 partition edges into padded bucket regions (zero-based
// cursors: reservation adds b*CAP). Blocks NP.. do label/id histogram.
__global__ void part_hist_kernel(const int* __restrict__ row, const int* __restrict__ col,
                                 const int* __restrict__ label, const int* __restrict__ id,
                                 int* __restrict__ colCursor, int* __restrict__ rowCursor,
                                 u32* __restrict__ S, u8* __restrict__ Sr,
                                 int* __restrict__ labCnt, int* __restrict__ cnt) {
    __shared__ int hc[NB], hr[NB], bc[NB], br[NB];
    __shared__ int h8[8];
    int t = threadIdx.x;
    if (blockIdx.x >= NP) {
        // ---- label/id histogram branch (98 blocks x 512 threads) ----
        if (t < 8) h8[t] = 0;
        __syncthreads();
        int n = (blockIdx.x - NP) * PT + t;
        if (n < N_NODES) atomicAdd(&h8[label[n]], 1);
        if (n < NUM_IDX) atomicAdd(&cnt[id[n]], 1);   // blocks 0..3 cover 2048 ids
        __syncthreads();
        if (t < 8 && h8[t] > 0) atomicAdd(&labCnt[t], h8[t]);
        return;
    }
    // ---- partition branch ----
    int p = blockIdx.x;
    for (int i = t; i < NB; i += PT) { hc[i] = 0; hr[i] = 0; }
    __syncthreads();
    int e0 = p * CHK, e1 = min(e0 + CHK, E_EDGES);
    int rr[EPT], cc[EPT];
    #pragma unroll
    for (int i = 0; i < EPT; ++i) {
        int e = e0 + t + i * PT;
        if (e < e1) {
            int r = row[e], c = col[e];
            rr[i] = r; cc[i] = c;
            atomicAdd(&hc[c >> 8], 1);
            atomicAdd(&hr[r >> 8], 1);
        }
    }
    __syncthreads();
    for (int i = t; i < NB; i += PT) {
        bc[i] = (hc[i] > 0) ? (i * CAP + atomicAdd(&colCursor[i], hc[i])) : 0;
        br[i] = (hr[i] > 0) ? (i * CAP + atomicAdd(&rowCursor[i], hr[i])) : 0;
    }
    __syncthreads();
    #pragma unroll
    for (int i = 0; i < EPT; ++i) {
        int e = e0 + t + i * PT;
        if (e < e1) {
            int r = rr[i], c = cc[i];
            int pc = atomicAdd(&bc[c >> 8], 1);
            S[pc] = ((u32)r << 8) | (u32)(c & 255);
            int pr = atomicAdd(&br[r >> 8], 1);
            Sr[pr] = (u8)(r & 255);
        }
    }
}

// K_B: blocks 0..NB-1 fine-CSR; NB..2NB-1 degree/dinv; 2NB.. label_fill.
__global__ void csr_fill_kernel(const u32* __restrict__ S, const u8* __restrict__ Sr,
                                const int* __restrict__ colCursor, const int* __restrict__ rowCursor,
                                int* __restrict__ s_beg, int* __restrict__ s_end,
                                u16* __restrict__ srcrow, float* __restrict__ dinv,
                                const int* __restrict__ label, const int* __restrict__ labCnt,
                                int* __restrict__ labOffset, int* __restrict__ nodeByLabel) {
    __shared__ int h[CPB], cur[CPB], sc[CPB];
    __shared__ int h8[8], base8[8], c28[8];
    int t = threadIdx.x;
    if (blockIdx.x >= 2 * NB) {
        // ---- label_fill branch (98 blocks x 512 threads) ----
        if (t < 8) { h8[t] = 0; c28[t] = 0; }
        __syncthreads();
        int n = (blockIdx.x - 2 * NB) * PT + t;
        int l = 0;
        if (n < N_NODES) { l = label[n]; atomicAdd(&h8[l], 1); }
        __syncthreads();
        if (t < 8 && h8[t] > 0) {
            int lb = 0;                          // labBase[l] = prefix of labCnt
            for (int i = 0; i < t; ++i) lb += labCnt[i];
            base8[t] = lb + atomicAdd(&labOffset[t], h8[t]);
        }
        __syncthreads();
        if (n < N_NODES) {
            int pos = base8[l] + atomicAdd(&c28[l], 1);
            nodeByLabel[pos] = n;
        }
        return;
    }
    if (blockIdx.x >= NB) {
        // ---- degree branch: LDS histogram of Sr bucket -> dinv ----
        int b = blockIdx.x - NB;
        if (t < CPB) h[t] = 0;
        __syncthreads();
        int e0 = b * CAP, e1 = b * CAP + rowCursor[b];
        for (int e = e0 + t; e < e1; e += PT) atomicAdd(&h[Sr[e]], 1);
        __syncthreads();
        if (t < CPB) {
            int n = b * CPB + t;
            if (n < N_NODES) dinv[n] = rsqrtf((float)(h[t] + 1));
        }
        return;
    }
    // ---- fine-CSR branch ----
    int b = blockIdx.x;
    if (t < CPB) h[t] = 0;
    __syncthreads();
    int e0 = b * CAP, e1 = b * CAP + colCursor[b];
    for (int e = e0 + t; e < e1; e += PT) atomicAdd(&h[S[e] & 255u], 1);
    __syncthreads();
    if (t < CPB) sc[t] = h[t];
    __syncthreads();
    for (int off = 1; off < CPB; off <<= 1) {
        int v = 0, a = 0;
        if (t < CPB) { v = sc[t]; a = (t >= off) ? sc[t - off] : 0; }
        __syncthreads();
        if (t < CPB) sc[t] = v + a;
        __syncthreads();
    }
    if (t < CPB) {
        int base = (t == 0) ? 0 : sc[t - 1];
        int gcol = b * CPB + t;
        if (gcol < N_NODES) {
            s_beg[gcol] = e0 + base;
            s_end[gcol] = e0 + base + h[t];
        }
        cur[t] = base;
    }
    __syncthreads();
    for (int e = e0 + t; e < e1; e += PT) {
        u32 v = S[e];
        int pos = atomicAdd(&cur[v & 255u], 1);
        srcrow[e0 + pos] = (u16)(v >> 8);
    }
}

// K6: label-grouped node transform -> bf16 messages.
// ONE wave (64 thr) x 2 channels/thread x GB=16 nodes. k-major LDS xsT[k][g]
// (stride XPAD=20: rows 16B-aligned for b128 broadcast, 8-way staging banks).
// Each w-load feeds 32 FMAs (vs 16 at GB=8) -> W L2-traffic halved.
__global__ void node_msg_kernel(const float* __restrict__ x,
                                const int* __restrict__ cnt,
                                const int* __restrict__ label,
                                const float* __restrict__ dinv,
                                const float* __restrict__ W,
                                const float* __restrict__ Wid,
                                const int* __restrict__ nodeByLabel,
                                __hip_bfloat16* __restrict__ msgb) {
    __shared__ float xsT[C_DIM][XPAD];     // [k][g], g<16; 10 KB
    __shared__ int nid[GB], lab[GB], cc[GB];
    int t = threadIdx.x;                   // 0..63
    int t2 = t + 64;
    if (t < GB) {
        int n = nodeByLabel[blockIdx.x * GB + t];
        nid[t] = n; lab[t] = label[n]; cc[t] = cnt[n];
    }
    __syncthreads();
    #pragma unroll
    for (int g = 0; g < GB; ++g) {
        xsT[t][g]  = __builtin_nontemporal_load(x + (size_t)nid[g] * C_DIM + t);
        xsT[t2][g] = __builtin_nontemporal_load(x + (size_t)nid[g] * C_DIM + t2);
    }
    __syncthreads();
    for (int g = 0; g < GB; ++g) {          // ego update (~4% of nodes)
        int c = cc[g];
        if (c > 0) {
            float a0 = 0.f, a1 = 0.f;
            #pragma unroll 8
            for (int k = 0; k < C_DIM; ++k) {
                float xv = xsT[k][g];
                a0 += xv * W[k * C_DIM + t];
                a1 += xv * W[k * C_DIM + t2];
            }
            __syncthreads();
            xsT[t][g]  += (float)c * a0;
            xsT[t2][g] += (float)c * a1;
            __syncthreads();
        }
    }
    float acc0[GB], acc1[GB];              // start from staged value (res)
    #pragma unroll
    for (int g = 0; g < GB; ++g) { acc0[g] = xsT[t][g]; acc1[g] = xsT[t2][g]; }
    if (lab[0] == lab[GB - 1]) {
        int L = lab[0];
        if (L > 0) {
            const float* Wl = Wid + (size_t)(L - 1) * C_DIM * C_DIM;
            for (int k = 0; k < C_DIM; ++k) {
                float w0 = Wl[k * C_DIM + t];
                float w1 = Wl[k * C_DIM + t2];
                f32x4 xa = *(const f32x4*)&xsT[k][0];    // broadcast b128 x4
                f32x4 xb = *(const f32x4*)&xsT[k][4];
                f32x4 xc = *(const f32x4*)&xsT[k][8];
                f32x4 xd = *(const f32x4*)&xsT[k][12];
                acc0[0]  += xa.x * w0; acc0[1]  += xa.y * w0;
                acc0[2]  += xa.z * w0; acc0[3]  += xa.w * w0;
                acc0[4]  += xb.x * w0; acc0[5]  += xb.y * w0;
                acc0[6]  += xb.z * w0; acc0[7]  += xb.w * w0;
                acc0[8]  += xc.x * w0; acc0[9]  += xc.y * w0;
                acc0[10] += xc.z * w0; acc0[11] += xc.w * w0;
                acc0[12] += xd.x * w0; acc0[13] += xd.y * w0;
                acc0[14] += xd.z * w0; acc0[15] += xd.w * w0;
                acc1[0]  += xa.x * w1; acc1[1]  += xa.y * w1;
                acc1[2]  += xa.z * w1; acc1[3]  += xa.w * w1;
                acc1[4]  += xb.x * w1; acc1[5]  += xb.y * w1;
                acc1[6]  += xb.z * w1; acc1[7]  += xb.w * w1;
                acc1[8]  += xc.x * w1; acc1[9]  += xc.y * w1;
                acc1[10] += xc.z * w1; acc1[11] += xc.w * w1;
                acc1[12] += xd.x * w1; acc1[13] += xd.y * w1;
                acc1[14] += xd.z * w1; acc1[15] += xd.w * w1;
            }
        }
    } else {
        for (int g = 0; g < GB; ++g) {
            int L = lab[g];
            if (L > 0) {
                const float* Wl = Wid + (size_t)(L - 1) * C_DIM * C_DIM;
                float a0 = 0.f, a1 = 0.f;
                #pragma unroll 8
                for (int k = 0; k < C_DIM; ++k) {
                    float xv = xsT[k][g];
                    a0 += xv * Wl[k * C_DIM + t];
                    a1 += xv * Wl[k * C_DIM + t2];
                }
                acc0[g] += a0; acc1[g] += a1;
            }
        }
    }
    #pragma unroll
    for (int g = 0; g < GB; ++g) {
        int n = nid[g];
        float di = dinv[n];
        msgb[(size_t)n * C_DIM + t]  = __float2bfloat16(di * acc0[g]);
        msgb[(size_t)n * C_DIM + t2] = __float2bfloat16(di * acc1[g]);
    }
}

// K7: gather + finalize (single-pass, r8 proven form). One wave per dest node;
// 4 edges in flight per wave. lane = (g,q): g = edge slot, q = channel quad.
__global__ void gather_kernel(const int* __restrict__ s_beg, const int* __restrict__ s_end,
                              const u16* __restrict__ srcrow,
                              const float* __restrict__ dinv,
                              const u32* __restrict__ m32,   // bf16x2-packed msg
                              float* __restrict__ out) {
    int wid  = threadIdx.x >> 6;
    int lane = threadIdx.x & 63;
    int g = lane >> 4;
    int q = lane & 15;
    int c = blockIdx.x * 4 + wid;
    int e0 = s_beg[c], e1 = s_end[c];
    const uint4* m4 = (const uint4*)m32;   // one node = 16 uint4

    float a0[4], a1[4];
    #pragma unroll
    for (int k = 0; k < 4; ++k) { a0[k] = 0.f; a1[k] = 0.f; }

    #define ACC4(U)                                                          \
        a0[0] += __uint_as_float((U).x << 16); a1[0] += __uint_as_float((U).x & 0xffff0000u); \
        a0[1] += __uint_as_float((U).y << 16); a1[1] += __uint_as_float((U).y & 0xffff0000u); \
        a0[2] += __uint_as_float((U).z << 16); a1[2] += __uint_as_float((U).z & 0xffff0000u); \
        a0[3] += __uint_as_float((U).w << 16); a1[3] += __uint_as_float((U).w & 0xffff0000u);

    int e = e0;
    for (; e + 8 <= e1; e += 8) {
        u32 r0 = srcrow[e + g];
        u32 r1 = srcrow[e + 4 + g];
        uint4 u0 = m4[r0 * 16u + (u32)q];
        uint4 u1 = m4[r1 * 16u + (u32)q];
        ACC4(u0);
        ACC4(u1);
    }
    if (e + 4 <= e1) {
        u32 r0 = srcrow[e + g];
        uint4 u0 = m4[r0 * 16u + (u32)q];
        ACC4(u0);
        e += 4;
    }
    if (g == 0) {
        // self-loop message (counted once via edge-slot 0 only)
        uint4 us = m4[(u32)c * 16u + (u32)q];
        ACC4(us);
        // tail (< 4 remaining edges)
        for (; e < e1; ++e) {
            u32 r = srcrow[e];
            uint4 u = m4[r * 16u + (u32)q];
            ACC4(u);
        }
    }
    #undef ACC4

    // reduce the 4 edge-slot groups: lanes l, l^16, l^32, l^48 hold the same quad q
    #pragma unroll
    for (int k = 0; k < 4; ++k) {
        a0[k] += __shfl_xor(a0[k], 16);
        a0[k] += __shfl_xor(a0[k], 32);
        a1[k] += __shfl_xor(a1[k], 16);
        a1[k] += __shfl_xor(a1[k], 32);
    }

    if (lane < 16) {
        float di = dinv[c];
        f32x4 o0, o1;
        o0.x = di * a0[0]; o0.y = di * a1[0]; o0.z = di * a0[1]; o0.w = di * a1[1];
        o1.x = di * a0[2]; o1.y = di * a1[2]; o1.z = di * a0[3]; o1.w = di * a1[3];
        f32x4* op = (f32x4*)(out + ((size_t)c << 7)) + (q << 1);
        __builtin_nontemporal_store(o0, op);
        __builtin_nontemporal_store(o1, op + 1);
    }
}

extern "C" void kernel_launch(void* const* d_in, const int* in_sizes, int n_in,
                              void* d_out, int out_size, void* d_ws, size_t ws_size,
                              hipStream_t stream) {
    const float* x     = (const float*)d_in[0];
    const int*   edge  = (const int*)d_in[1];   // [2][E]
    const int*   id    = (const int*)d_in[2];
    const int*   label = (const int*)d_in[3];
    const float* W     = (const float*)d_in[4];
    const float* Wid   = (const float*)d_in[5];
    float*       out   = (float*)d_out;

    const int* row = edge;
    const int* col = edge + E_EDGES;

    // ws layout:
    // msgb[N*C] bf16 | S[NB*CAP] u32 | srcrow[NB*CAP] u16 | Sr[NB*CAP] u8 |
    // s_beg[N] | s_end[N] | nodeByLabel[N] | dinv[N] f32 |
    // ZERO{ cnt[N] | labCnt[8] | labOffset[8] | colCursor[NB] | rowCursor[NB] }
    __hip_bfloat16* msgb = (__hip_bfloat16*)d_ws;
    u32* S           = (u32*)(msgb + (size_t)N_NODES * C_DIM);
    u16* srcrow      = (u16*)(S + (size_t)NB * CAP);
    u8*  Sr          = (u8*)(srcrow + (size_t)NB * CAP);
    int* s_beg       = (int*)(Sr + (size_t)NB * CAP);
    int* s_end       = s_beg + N_NODES;
    int* nodeByLabel = s_end + N_NODES;
    float* dinv      = (float*)(nodeByLabel + N_NODES);
    int* cnt         = (int*)(dinv + N_NODES);
    int* labCnt      = cnt + N_NODES;
    int* labOffset   = labCnt + 8;
    int* colCursor   = labOffset + 8;
    int* rowCursor   = colCursor + NB;

    hipMemsetAsync(cnt, 0, ((size_t)N_NODES + 16 + 2 * NB) * sizeof(int), stream);

    part_hist_kernel<<<NP + NLB, PT, 0, stream>>>(row, col, label, id,
                                                  colCursor, rowCursor, S, Sr, labCnt, cnt);
    csr_fill_kernel <<<2 * NB + NLB, PT, 0, stream>>>(S, Sr, colCursor, rowCursor,
                                                      s_beg, s_end, srcrow, dinv,
                                                      label, labCnt, labOffset, nodeByLabel);
    node_msg_kernel <<<N_NODES / GB, 64, 0, stream>>>(x, cnt, label, dinv, W, Wid,
                                                      nodeByLabel, msgb);
    gather_kernel   <<<N_NODES / 4, 256, 0, stream>>>(s_beg, s_end, srcrow, dinv,
                                                      (const u32*)msgb, out);
}

// Round 13
// 229.255 us; speedup vs baseline: 1.0324x; 1.0324x over previous
//
#include <hip/hip_runtime.h>
#include <hip/hip_bf16.h>

typedef unsigned int   u32;
typedef unsigned short u16;
typedef unsigned char  u8;
typedef float f32x2 __attribute__((ext_vector_type(2)));
typedef float f32x4 __attribute__((ext_vector_type(4)));

#define N_NODES 50000
#define C_DIM   128
#define E_EDGES 1600000
#define NUM_IDX 2048

#define CPB 256                    // cols per coarse bucket (key >> 8)
#define NB  196                    // ceil(N/CPB)
#define CAP 9216                   // padded capacity per bucket (mean 8192, sigma ~90)
#define CHK 8192                   // edges per chunk
#define NP  196                    // ceil(E/CHK)
#define PT  512                    // threads for partition-family kernels
#define EPT 16                     // edges per thread in partition (CHK/PT)
#define GB  8                      // nodes per label-matmul block (r12: 16 regressed)
#define NLB 98                     // label-stripe blocks of 512 (ceil(N/512))

// LESSONS (journal):
// r5: device-scope global atomics on MI355X are HBM-side RMW. Keep hists in LDS.
// r6: f32x4-casting per-g LDS reads in double-unrolled loops -> scratch spill
//     (fix: k-major LDS layout so vector reads are broadcast, accs static-idx).
// r7: node_msg LDS-issue bound; k-major staging (xsT[k][g]) broadcast b128.
// r8: gather one-shot is L3-random bound (149MB @ 2.7TB/s = 54us floor).
// r10: 4-pass channel-split gather REGRESSED: no L2 residency vs streaming
//      co-tenants. 1 wave/block for node_msg (no duplicate broadcasts).
// r12: GB=16 REGRESSED (occupancy 40%->14%, node_msg 45->68us): node_msg is
//      wave-count latency-hiding bound. Never trade occupancy for reuse here.
//      This round: channel pairing (2t,2t+1) -> f32x2 W loads, packed stores.

// K_A: blocks 0..NP-1 partition edges into padded bucket regions (zero-based
// cursors: reservation adds b*CAP). Blocks NP.. do label/id histogram.
__global__ void part_hist_kernel(const int* __restrict__ row, const int* __restrict__ col,
                                 const int* __restrict__ label, const int* __restrict__ id,
                                 int* __restrict__ colCursor, int* __restrict__ rowCursor,
                                 u32* __restrict__ S, u8* __restrict__ Sr,
                                 int* __restrict__ labCnt, int* __restrict__ cnt) {
    __shared__ int hc[NB], hr[NB], bc[NB], br[NB];
    __shared__ int h8[8];
    int t = threadIdx.x;
    if (blockIdx.x >= NP) {
        // ---- label/id histogram branch (98 blocks x 512 threads) ----
        if (t < 8) h8[t] = 0;
        __syncthreads();
        int n = (blockIdx.x - NP) * PT + t;
        if (n < N_NODES) atomicAdd(&h8[label[n]], 1);
        if (n < NUM_IDX) atomicAdd(&cnt[id[n]], 1);   // blocks 0..3 cover 2048 ids
        __syncthreads();
        if (t < 8 && h8[t] > 0) atomicAdd(&labCnt[t], h8[t]);
        return;
    }
    // ---- partition branch ----
    int p = blockIdx.x;
    for (int i = t; i < NB; i += PT) { hc[i] = 0; hr[i] = 0; }
    __syncthreads();
    int e0 = p * CHK, e1 = min(e0 + CHK, E_EDGES);
    int rr[EPT], cc[EPT];
    #pragma unroll
    for (int i = 0; i < EPT; ++i) {
        int e = e0 + t + i * PT;
        if (e < e1) {
            int r = row[e], c = col[e];
            rr[i] = r; cc[i] = c;
            atomicAdd(&hc[c >> 8], 1);
            atomicAdd(&hr[r >> 8], 1);
        }
    }
    __syncthreads();
    for (int i = t; i < NB; i += PT) {
        bc[i] = (hc[i] > 0) ? (i * CAP + atomicAdd(&colCursor[i], hc[i])) : 0;
        br[i] = (hr[i] > 0) ? (i * CAP + atomicAdd(&rowCursor[i], hr[i])) : 0;
    }
    __syncthreads();
    #pragma unroll
    for (int i = 0; i < EPT; ++i) {
        int e = e0 + t + i * PT;
        if (e < e1) {
            int r = rr[i], c = cc[i];
            int pc = atomicAdd(&bc[c >> 8], 1);
            S[pc] = ((u32)r << 8) | (u32)(c & 255);
            int pr = atomicAdd(&br[r >> 8], 1);
            Sr[pr] = (u8)(r & 255);
        }
    }
}

// K_B: blocks 0..NB-1 fine-CSR; NB..2NB-1 degree/dinv; 2NB.. label_fill.
__global__ void csr_fill_kernel(const u32* __restrict__ S, const u8* __restrict__ Sr,
                                const int* __restrict__ colCursor, const int* __restrict__ rowCursor,
                                int* __restrict__ s_beg, int* __restrict__ s_end,
                                u16* __restrict__ srcrow, float* __restrict__ dinv,
                                const int* __restrict__ label, const int* __restrict__ labCnt,
                                int* __restrict__ labOffset, int* __restrict__ nodeByLabel) {
    __shared__ int h[CPB], cur[CPB], sc[CPB];
    __shared__ int h8[8], base8[8], c28[8];
    int t = threadIdx.x;
    if (blockIdx.x >= 2 * NB) {
        // ---- label_fill branch (98 blocks x 512 threads) ----
        if (t < 8) { h8[t] = 0; c28[t] = 0; }
        __syncthreads();
        int n = (blockIdx.x - 2 * NB) * PT + t;
        int l = 0;
        if (n < N_NODES) { l = label[n]; atomicAdd(&h8[l], 1); }
        __syncthreads();
        if (t < 8 && h8[t] > 0) {
            int lb = 0;                          // labBase[l] = prefix of labCnt
            for (int i = 0; i < t; ++i) lb += labCnt[i];
            base8[t] = lb + atomicAdd(&labOffset[t], h8[t]);
        }
        __syncthreads();
        if (n < N_NODES) {
            int pos = base8[l] + atomicAdd(&c28[l], 1);
            nodeByLabel[pos] = n;
        }
        return;
    }
    if (blockIdx.x >= NB) {
        // ---- degree branch: LDS histogram of Sr bucket -> dinv ----
        int b = blockIdx.x - NB;
        if (t < CPB) h[t] = 0;
        __syncthreads();
        int e0 = b * CAP, e1 = b * CAP + rowCursor[b];
        for (int e = e0 + t; e < e1; e += PT) atomicAdd(&h[Sr[e]], 1);
        __syncthreads();
        if (t < CPB) {
            int n = b * CPB + t;
            if (n < N_NODES) dinv[n] = rsqrtf((float)(h[t] + 1));
        }
        return;
    }
    // ---- fine-CSR branch ----
    int b = blockIdx.x;
    if (t < CPB) h[t] = 0;
    __syncthreads();
    int e0 = b * CAP, e1 = b * CAP + colCursor[b];
    for (int e = e0 + t; e < e1; e += PT) atomicAdd(&h[S[e] & 255u], 1);
    __syncthreads();
    if (t < CPB) sc[t] = h[t];
    __syncthreads();
    for (int off = 1; off < CPB; off <<= 1) {
        int v = 0, a = 0;
        if (t < CPB) { v = sc[t]; a = (t >= off) ? sc[t - off] : 0; }
        __syncthreads();
        if (t < CPB) sc[t] = v + a;
        __syncthreads();
    }
    if (t < CPB) {
        int base = (t == 0) ? 0 : sc[t - 1];
        int gcol = b * CPB + t;
        if (gcol < N_NODES) {
            s_beg[gcol] = e0 + base;
            s_end[gcol] = e0 + base + h[t];
        }
        cur[t] = base;
    }
    __syncthreads();
    for (int e = e0 + t; e < e1; e += PT) {
        u32 v = S[e];
        int pos = atomicAdd(&cur[v & 255u], 1);
        srcrow[e0 + pos] = (u16)(v >> 8);
    }
}

// K6: label-grouped node transform -> bf16 messages.
// ONE wave (64 thr) x GB=8 nodes; thread t owns channels (2t, 2t+1):
// W/Wid loads are f32x2 (1 VMEM instr per k, was 2), msgb store is one
// packed u32 (2xbf16, coalesced 256B/wave). r11 structure otherwise.
__global__ void node_msg_kernel(const float* __restrict__ x,
                                const int* __restrict__ cnt,
                                const int* __restrict__ label,
                                const float* __restrict__ dinv,
                                const float* __restrict__ W,
                                const float* __restrict__ Wid,
                                const int* __restrict__ nodeByLabel,
                                __hip_bfloat16* __restrict__ msgb) {
    __shared__ float xsT[C_DIM][GB];       // [k][g], 4 KB
    __shared__ int nid[GB], lab[GB], cc[GB];
    int t = threadIdx.x;                   // 0..63
    int c0 = 2 * t, c1 = 2 * t + 1;        // owned channels
    if (t < GB) {
        int n = nodeByLabel[blockIdx.x * GB + t];
        nid[t] = n; lab[t] = label[n]; cc[t] = cnt[n];
    }
    __syncthreads();
    #pragma unroll
    for (int g = 0; g < GB; ++g) {
        f32x2 xv = *(const f32x2*)(x + (size_t)nid[g] * C_DIM + c0);
        xsT[c0][g] = xv.x;
        xsT[c1][g] = xv.y;
    }
    __syncthreads();
    for (int g = 0; g < GB; ++g) {          // ego update (~4% of nodes)
        int c = cc[g];
        if (c > 0) {
            float a0 = 0.f, a1 = 0.f;
            #pragma unroll 8
            for (int k = 0; k < C_DIM; ++k) {
                float xv = xsT[k][g];
                f32x2 w = *(const f32x2*)(W + k * C_DIM + c0);
                a0 += xv * w.x;
                a1 += xv * w.y;
            }
            __syncthreads();
            xsT[c0][g] += (float)c * a0;
            xsT[c1][g] += (float)c * a1;
            __syncthreads();
        }
    }
    float acc0[GB], acc1[GB];
    #pragma unroll
    for (int g = 0; g < GB; ++g) { acc0[g] = xsT[c0][g]; acc1[g] = xsT[c1][g]; }
    if (lab[0] == lab[GB - 1]) {
        int L = lab[0];
        if (L > 0) {
            const float* Wl = Wid + (size_t)(L - 1) * C_DIM * C_DIM;
            for (int k = 0; k < C_DIM; ++k) {
                f32x2 w = *(const f32x2*)(Wl + k * C_DIM + c0);
                f32x4 xa = *(const f32x4*)&xsT[k][0];    // broadcast b128
                f32x4 xb = *(const f32x4*)&xsT[k][4];    // broadcast b128
                acc0[0] += xa.x * w.x; acc0[1] += xa.y * w.x;
                acc0[2] += xa.z * w.x; acc0[3] += xa.w * w.x;
                acc0[4] += xb.x * w.x; acc0[5] += xb.y * w.x;
                acc0[6] += xb.z * w.x; acc0[7] += xb.w * w.x;
                acc1[0] += xa.x * w.y; acc1[1] += xa.y * w.y;
                acc1[2] += xa.z * w.y; acc1[3] += xa.w * w.y;
                acc1[4] += xb.x * w.y; acc1[5] += xb.y * w.y;
                acc1[6] += xb.z * w.y; acc1[7] += xb.w * w.y;
            }
        }
    } else {
        for (int g = 0; g < GB; ++g) {
            int L = lab[g];
            if (L > 0) {
                const float* Wl = Wid + (size_t)(L - 1) * C_DIM * C_DIM;
                float a0 = 0.f, a1 = 0.f;
                #pragma unroll 8
                for (int k = 0; k < C_DIM; ++k) {
                    float xv = xsT[k][g];
                    f32x2 w = *(const f32x2*)(Wl + k * C_DIM + c0);
                    a0 += xv * w.x;
                    a1 += xv * w.y;
                }
                acc0[g] += a0; acc1[g] += a1;
            }
        }
    }
    u32* m32 = (u32*)msgb;                 // node = 64 u32 (bf16 pairs)
    #pragma unroll
    for (int g = 0; g < GB; ++g) {
        int n = nid[g];
        float di = dinv[n];
        __hip_bfloat16 b0 = __float2bfloat16(di * acc0[g]);
        __hip_bfloat16 b1 = __float2bfloat16(di * acc1[g]);
        u32 lo = *reinterpret_cast<unsigned short*>(&b0);
        u32 hi = *reinterpret_cast<unsigned short*>(&b1);
        m32[(size_t)n * 64 + t] = lo | (hi << 16);
    }
}

// K7: gather + finalize (single-pass, r8 proven form). One wave per dest node;
// 4 edges in flight per wave. lane = (g,q): g = edge slot, q = channel quad.
__global__ void gather_kernel(const int* __restrict__ s_beg, const int* __restrict__ s_end,
                              const u16* __restrict__ srcrow,
                              const float* __restrict__ dinv,
                              const u32* __restrict__ m32,   // bf16x2-packed msg
                              float* __restrict__ out) {
    int wid  = threadIdx.x >> 6;
    int lane = threadIdx.x & 63;
    int g = lane >> 4;
    int q = lane & 15;
    int c = blockIdx.x * 4 + wid;
    int e0 = s_beg[c], e1 = s_end[c];
    const uint4* m4 = (const uint4*)m32;   // one node = 16 uint4

    float a0[4], a1[4];
    #pragma unroll
    for (int k = 0; k < 4; ++k) { a0[k] = 0.f; a1[k] = 0.f; }

    #define ACC4(U)                                                          \
        a0[0] += __uint_as_float((U).x << 16); a1[0] += __uint_as_float((U).x & 0xffff0000u); \
        a0[1] += __uint_as_float((U).y << 16); a1[1] += __uint_as_float((U).y & 0xffff0000u); \
        a0[2] += __uint_as_float((U).z << 16); a1[2] += __uint_as_float((U).z & 0xffff0000u); \
        a0[3] += __uint_as_float((U).w << 16); a1[3] += __uint_as_float((U).w & 0xffff0000u);

    int e = e0;
    for (; e + 8 <= e1; e += 8) {
        u32 r0 = srcrow[e + g];
        u32 r1 = srcrow[e + 4 + g];
        uint4 u0 = m4[r0 * 16u + (u32)q];
        uint4 u1 = m4[r1 * 16u + (u32)q];
        ACC4(u0);
        ACC4(u1);
    }
    if (e + 4 <= e1) {
        u32 r0 = srcrow[e + g];
        uint4 u0 = m4[r0 * 16u + (u32)q];
        ACC4(u0);
        e += 4;
    }
    if (g == 0) {
        // self-loop message (counted once via edge-slot 0 only)
        uint4 us = m4[(u32)c * 16u + (u32)q];
        ACC4(us);
        // tail (< 4 remaining edges)
        for (; e < e1; ++e) {
            u32 r = srcrow[e];
            uint4 u = m4[r * 16u + (u32)q];
            ACC4(u);
        }
    }
    #undef ACC4

    // reduce the 4 edge-slot groups: lanes l, l^16, l^32, l^48 hold the same quad q
    #pragma unroll
    for (int k = 0; k < 4; ++k) {
        a0[k] += __shfl_xor(a0[k], 16);
        a0[k] += __shfl_xor(a0[k], 32);
        a1[k] += __shfl_xor(a1[k], 16);
        a1[k] += __shfl_xor(a1[k], 32);
    }

    if (lane < 16) {
        float di = dinv[c];
        f32x4 o0, o1;
        o0.x = di * a0[0]; o0.y = di * a1[0]; o0.z = di * a0[1]; o0.w = di * a1[1];
        o1.x = di * a0[2]; o1.y = di * a1[2]; o1.z = di * a0[3]; o1.w = di * a1[3];
        // channels interleave as (2j, 2j+1) pairs per u32 j — matches msgb pack
        f32x4* op = (f32x4*)(out + ((size_t)c << 7)) + (q << 1);
        __builtin_nontemporal_store(o0, op);
        __builtin_nontemporal_store(o1, op + 1);
    }
}

extern "C" void kernel_launch(void* const* d_in, const int* in_sizes, int n_in,
                              void* d_out, int out_size, void* d_ws, size_t ws_size,
                              hipStream_t stream) {
    const float* x     = (const float*)d_in[0];
    const int*   edge  = (const int*)d_in[1];   // [2][E]
    const int*   id    = (const int*)d_in[2];
    const int*   label = (const int*)d_in[3];
    const float* W     = (const float*)d_in[4];
    const float* Wid   = (const float*)d_in[5];
    float*       out   = (float*)d_out;

    const int* row = edge;
    const int* col = edge + E_EDGES;

    // NOTE on channel layout: node_msg packs msgb u32 j = channels (2j, 2j+1).
    // gather unpacks u32 -> (lo, hi) = (even, odd) channel and stores
    // out[c][2j] = lo-sum, out[c][2j+1] = hi-sum — consistent, since gather's
    // o0/o1 interleave (a0[k], a1[k]) pairs exactly in u32 order.
    __hip_bfloat16* msgb = (__hip_bfloat16*)d_ws;
    u32* S           = (u32*)(msgb + (size_t)N_NODES * C_DIM);
    u16* srcrow      = (u16*)(S + (size_t)NB * CAP);
    u8*  Sr          = (u8*)(srcrow + (size_t)NB * CAP);
    int* s_beg       = (int*)(Sr + (size_t)NB * CAP);
    int* s_end       = s_beg + N_NODES;
    int* nodeByLabel = s_end + N_NODES;
    float* dinv      = (float*)(nodeByLabel + N_NODES);
    int* cnt         = (int*)(dinv + N_NODES);
    int* labCnt      = cnt + N_NODES;
    int* labOffset   = labCnt + 8;
    int* colCursor   = labOffset + 8;
    int* rowCursor   = colCursor + NB;

    hipMemsetAsync(cnt, 0, ((size_t)N_NODES + 16 + 2 * NB) * sizeof(int), stream);

    part_hist_kernel<<<NP + NLB, PT, 0, stream>>>(row, col, label, id,
                                                  colCursor, rowCursor, S, Sr, labCnt, cnt);
    csr_fill_kernel <<<2 * NB + NLB, PT, 0, stream>>>(S, Sr, colCursor, rowCursor,
                                                      s_beg, s_end, srcrow, dinv,
                                                      label, labCnt, labOffset, nodeByLabel);
    node_msg_kernel <<<N_NODES / GB, 64, 0, stream>>>(x, cnt, label, dinv, W, Wid,
                                                      nodeByLabel, msgb);
    gather_kernel   <<<N_NODES / 4, 256, 0, stream>>>(s_beg, s_end, srcrow, dinv,
                                                      (const u32*)msgb, out);
}

// Round 14
// 221.144 us; speedup vs baseline: 1.0703x; 1.0367x over previous
//
#include <hip/hip_runtime.h>
#include <hip/hip_bf16.h>

typedef unsigned int   u32;
typedef unsigned short u16;
typedef unsigned char  u8;
typedef float f32x2 __attribute__((ext_vector_type(2)));
typedef float f32x4 __attribute__((ext_vector_type(4)));

#define N_NODES 50000
#define C_DIM   128
#define E_EDGES 1600000
#define NUM_IDX 2048

#define CPB 256                    // cols per coarse bucket (key >> 8)
#define NB  196                    // ceil(N/CPB)
#define CAP 9216                   // padded capacity per bucket (mean 8192, sigma ~90)
#define CHK 8192                   // edges per chunk
#define NP  196                    // ceil(E/CHK)
#define PT  512                    // threads for partition-family kernels
#define EPT 16                     // edges per thread in partition (CHK/PT)
#define GB  8                      // nodes per label-matmul group
#define GPB 4                      // independent 1-wave groups per 256-thr block
#define NMB 1563                   // ceil(N / (GB*GPB))
#define NLB 98                     // label-stripe blocks of 512 (ceil(N/512))

// LESSONS (journal):
// r5: device-scope global atomics on MI355X are HBM-side RMW. Keep hists in LDS.
// r6: f32x4-casting per-g LDS reads in double-unrolled loops -> scratch spill.
// r7: node_msg k-major staging (xsT[k][g]) -> broadcast b128 reads.
// r8: gather one-shot is L3-random bound (149MB @ 2.7TB/s = 54us floor).
// r10: channel-split gather REGRESSED (no L2 residency vs streaming tenants).
// r12: GB=16 REGRESSED (occupancy 40->14%): node_msg is latency-hiding bound.
// r13: channel pairing (2t,2t+1) REGRESSED: staging rows 32B apart -> 16-way
//      bank conflict (1.14M cycles). Keep (t,t+64) channel split.
//      This round: 4 independent waves per 256-thr block (own LDS slabs) to
//      beat the ~16 workgroup-slot/CU cap; barriers made count-uniform.

// K_A: blocks 0..NP-1 partition edges into padded bucket regions (zero-based
// cursors: reservation adds b*CAP). Blocks NP.. do label/id histogram.
__global__ void part_hist_kernel(const int* __restrict__ row, const int* __restrict__ col,
                                 const int* __restrict__ label, const int* __restrict__ id,
                                 int* __restrict__ colCursor, int* __restrict__ rowCursor,
                                 u32* __restrict__ S, u8* __restrict__ Sr,
                                 int* __restrict__ labCnt, int* __restrict__ cnt) {
    __shared__ int hc[NB], hr[NB], bc[NB], br[NB];
    __shared__ int h8[8];
    int t = threadIdx.x;
    if (blockIdx.x >= NP) {
        // ---- label/id histogram branch (98 blocks x 512 threads) ----
        if (t < 8) h8[t] = 0;
        __syncthreads();
        int n = (blockIdx.x - NP) * PT + t;
        if (n < N_NODES) atomicAdd(&h8[label[n]], 1);
        if (n < NUM_IDX) atomicAdd(&cnt[id[n]], 1);   // blocks 0..3 cover 2048 ids
        __syncthreads();
        if (t < 8 && h8[t] > 0) atomicAdd(&labCnt[t], h8[t]);
        return;
    }
    // ---- partition branch ----
    int p = blockIdx.x;
    for (int i = t; i < NB; i += PT) { hc[i] = 0; hr[i] = 0; }
    __syncthreads();
    int e0 = p * CHK, e1 = min(e0 + CHK, E_EDGES);
    int rr[EPT], cc[EPT];
    #pragma unroll
    for (int i = 0; i < EPT; ++i) {
        int e = e0 + t + i * PT;
        if (e < e1) {
            int r = row[e], c = col[e];
            rr[i] = r; cc[i] = c;
            atomicAdd(&hc[c >> 8], 1);
            atomicAdd(&hr[r >> 8], 1);
        }
    }
    __syncthreads();
    for (int i = t; i < NB; i += PT) {
        bc[i] = (hc[i] > 0) ? (i * CAP + atomicAdd(&colCursor[i], hc[i])) : 0;
        br[i] = (hr[i] > 0) ? (i * CAP + atomicAdd(&rowCursor[i], hr[i])) : 0;
    }
    __syncthreads();
    #pragma unroll
    for (int i = 0; i < EPT; ++i) {
        int e = e0 + t + i * PT;
        if (e < e1) {
            int r = rr[i], c = cc[i];
            int pc = atomicAdd(&bc[c >> 8], 1);
            S[pc] = ((u32)r << 8) | (u32)(c & 255);
            int pr = atomicAdd(&br[r >> 8], 1);
            Sr[pr] = (u8)(r & 255);
        }
    }
}

// K_B: blocks 0..NB-1 fine-CSR; NB..2NB-1 degree/dinv; 2NB.. label_fill.
__global__ void csr_fill_kernel(const u32* __restrict__ S, const u8* __restrict__ Sr,
                                const int* __restrict__ colCursor, const int* __restrict__ rowCursor,
                                int* __restrict__ s_beg, int* __restrict__ s_end,
                                u16* __restrict__ srcrow, float* __restrict__ dinv,
                                const int* __restrict__ label, const int* __restrict__ labCnt,
                                int* __restrict__ labOffset, int* __restrict__ nodeByLabel) {
    __shared__ int h[CPB], cur[CPB], sc[CPB];
    __shared__ int h8[8], base8[8], c28[8];
    int t = threadIdx.x;
    if (blockIdx.x >= 2 * NB) {
        // ---- label_fill branch (98 blocks x 512 threads) ----
        if (t < 8) { h8[t] = 0; c28[t] = 0; }
        __syncthreads();
        int n = (blockIdx.x - 2 * NB) * PT + t;
        int l = 0;
        if (n < N_NODES) { l = label[n]; atomicAdd(&h8[l], 1); }
        __syncthreads();
        if (t < 8 && h8[t] > 0) {
            int lb = 0;                          // labBase[l] = prefix of labCnt
            for (int i = 0; i < t; ++i) lb += labCnt[i];
            base8[t] = lb + atomicAdd(&labOffset[t], h8[t]);
        }
        __syncthreads();
        if (n < N_NODES) {
            int pos = base8[l] + atomicAdd(&c28[l], 1);
            nodeByLabel[pos] = n;
        }
        return;
    }
    if (blockIdx.x >= NB) {
        // ---- degree branch: LDS histogram of Sr bucket -> dinv ----
        int b = blockIdx.x - NB;
        if (t < CPB) h[t] = 0;
        __syncthreads();
        int e0 = b * CAP, e1 = b * CAP + rowCursor[b];
        for (int e = e0 + t; e < e1; e += PT) atomicAdd(&h[Sr[e]], 1);
        __syncthreads();
        if (t < CPB) {
            int n = b * CPB + t;
            if (n < N_NODES) dinv[n] = rsqrtf((float)(h[t] + 1));
        }
        return;
    }
    // ---- fine-CSR branch ----
    int b = blockIdx.x;
    if (t < CPB) h[t] = 0;
    __syncthreads();
    int e0 = b * CAP, e1 = b * CAP + colCursor[b];
    for (int e = e0 + t; e < e1; e += PT) atomicAdd(&h[S[e] & 255u], 1);
    __syncthreads();
    if (t < CPB) sc[t] = h[t];
    __syncthreads();
    for (int off = 1; off < CPB; off <<= 1) {
        int v = 0, a = 0;
        if (t < CPB) { v = sc[t]; a = (t >= off) ? sc[t - off] : 0; }
        __syncthreads();
        if (t < CPB) sc[t] = v + a;
        __syncthreads();
    }
    if (t < CPB) {
        int base = (t == 0) ? 0 : sc[t - 1];
        int gcol = b * CPB + t;
        if (gcol < N_NODES) {
            s_beg[gcol] = e0 + base;
            s_end[gcol] = e0 + base + h[t];
        }
        cur[t] = base;
    }
    __syncthreads();
    for (int e = e0 + t; e < e1; e += PT) {
        u32 v = S[e];
        int pos = atomicAdd(&cur[v & 255u], 1);
        srcrow[e0 + pos] = (u16)(v >> 8);
    }
}

// K6: label-grouped node transform -> bf16 messages.
// 256 threads = 4 INDEPENDENT 1-wave groups (wave w: own LDS slab, own 8
// nodes, channels (t, t+64) — r11 proven shape). Beats the ~16 workgroup-
// slot/CU cap that limited 64-thread blocks to 40% occupancy (r13 lesson).
// All __syncthreads() are unconditional (uniform count across waves).
__global__ void node_msg_kernel(const float* __restrict__ x,
                                const int* __restrict__ cnt,
                                const int* __restrict__ label,
                                const float* __restrict__ dinv,
                                const float* __restrict__ W,
                                const float* __restrict__ Wid,
                                const int* __restrict__ nodeByLabel,
                                __hip_bfloat16* __restrict__ msgb) {
    __shared__ float xsT[GPB][C_DIM][GB];    // per-wave slab: [k][g], 4 KB each
    __shared__ int nid[GPB][GB], lab[GPB][GB], cc[GPB][GB];
    int w  = threadIdx.x >> 6;               // wave / group slot
    int t  = threadIdx.x & 63;
    int t2 = t + 64;
    int base = (blockIdx.x * GPB + w) * GB;  // first nodeByLabel idx of group
    if (t < GB) {
        int idx = base + t;
        int ok = (idx < N_NODES);
        int n = ok ? nodeByLabel[idx] : 0;
        nid[w][t] = n;
        lab[w][t] = ok ? label[n] : 0;
        cc[w][t]  = ok ? cnt[n] : 0;
    }
    __syncthreads();
    #pragma unroll
    for (int g = 0; g < GB; ++g) {
        xsT[w][t][g]  = __builtin_nontemporal_load(x + (size_t)nid[w][g] * C_DIM + t);
        xsT[w][t2][g] = __builtin_nontemporal_load(x + (size_t)nid[w][g] * C_DIM + t2);
    }
    __syncthreads();
    // ego update (~4% of nodes): compute predicated, barriers unconditional.
    // Iteration g reads column g then (post-barrier) writes column g; later
    // iterations touch disjoint columns, so one barrier per g suffices.
    for (int g = 0; g < GB; ++g) {
        int c = cc[w][g];
        float a0 = 0.f, a1 = 0.f;
        if (c > 0) {
            #pragma unroll 8
            for (int k = 0; k < C_DIM; ++k) {
                float xv = xsT[w][k][g];
                a0 += xv * W[k * C_DIM + t];
                a1 += xv * W[k * C_DIM + t2];
            }
        }
        __syncthreads();
        if (c > 0) {
            xsT[w][t][g]  += (float)c * a0;
            xsT[w][t2][g] += (float)c * a1;
        }
    }
    __syncthreads();
    float acc0[GB], acc1[GB];
    #pragma unroll
    for (int g = 0; g < GB; ++g) { acc0[g] = xsT[w][t][g]; acc1[g] = xsT[w][t2][g]; }
    if (lab[w][0] == lab[w][GB - 1]) {
        int L = lab[w][0];
        if (L > 0) {
            const float* Wl = Wid + (size_t)(L - 1) * C_DIM * C_DIM;
            for (int k = 0; k < C_DIM; ++k) {
                float w0 = Wl[k * C_DIM + t];
                float w1 = Wl[k * C_DIM + t2];
                f32x4 xa = *(const f32x4*)&xsT[w][k][0];   // broadcast b128
                f32x4 xb = *(const f32x4*)&xsT[w][k][4];   // broadcast b128
                acc0[0] += xa.x * w0; acc0[1] += xa.y * w0;
                acc0[2] += xa.z * w0; acc0[3] += xa.w * w0;
                acc0[4] += xb.x * w0; acc0[5] += xb.y * w0;
                acc0[6] += xb.z * w0; acc0[7] += xb.w * w0;
                acc1[0] += xa.x * w1; acc1[1] += xa.y * w1;
                acc1[2] += xa.z * w1; acc1[3] += xa.w * w1;
                acc1[4] += xb.x * w1; acc1[5] += xb.y * w1;
                acc1[6] += xb.z * w1; acc1[7] += xb.w * w1;
            }
        }
    } else {
        for (int g = 0; g < GB; ++g) {
            int L = lab[w][g];
            if (L > 0) {
                const float* Wl = Wid + (size_t)(L - 1) * C_DIM * C_DIM;
                float a0 = 0.f, a1 = 0.f;
                #pragma unroll 8
                for (int k = 0; k < C_DIM; ++k) {
                    float xv = xsT[w][k][g];
                    a0 += xv * Wl[k * C_DIM + t];
                    a1 += xv * Wl[k * C_DIM + t2];
                }
                acc0[g] += a0; acc1[g] += a1;
            }
        }
    }
    #pragma unroll
    for (int g = 0; g < GB; ++g) {
        if (base + g < N_NODES) {
            int n = nid[w][g];
            float di = dinv[n];
            msgb[(size_t)n * C_DIM + t]  = __float2bfloat16(di * acc0[g]);
            msgb[(size_t)n * C_DIM + t2] = __float2bfloat16(di * acc1[g]);
        }
    }
}

// K7: gather + finalize (single-pass, r8 proven form). One wave per dest node;
// 4 edges in flight per wave. lane = (g,q): g = edge slot, q = channel quad.
__global__ void gather_kernel(const int* __restrict__ s_beg, const int* __restrict__ s_end,
                              const u16* __restrict__ srcrow,
                              const float* __restrict__ dinv,
                              const u32* __restrict__ m32,   // bf16x2-packed msg
                              float* __restrict__ out) {
    int wid  = threadIdx.x >> 6;
    int lane = threadIdx.x & 63;
    int g = lane >> 4;
    int q = lane & 15;
    int c = blockIdx.x * 4 + wid;
    int e0 = s_beg[c], e1 = s_end[c];
    const uint4* m4 = (const uint4*)m32;   // one node = 16 uint4

    float a0[4], a1[4];
    #pragma unroll
    for (int k = 0; k < 4; ++k) { a0[k] = 0.f; a1[k] = 0.f; }

    #define ACC4(U)                                                          \
        a0[0] += __uint_as_float((U).x << 16); a1[0] += __uint_as_float((U).x & 0xffff0000u); \
        a0[1] += __uint_as_float((U).y << 16); a1[1] += __uint_as_float((U).y & 0xffff0000u); \
        a0[2] += __uint_as_float((U).z << 16); a1[2] += __uint_as_float((U).z & 0xffff0000u); \
        a0[3] += __uint_as_float((U).w << 16); a1[3] += __uint_as_float((U).w & 0xffff0000u);

    int e = e0;
    for (; e + 8 <= e1; e += 8) {
        u32 r0 = srcrow[e + g];
        u32 r1 = srcrow[e + 4 + g];
        uint4 u0 = m4[r0 * 16u + (u32)q];
        uint4 u1 = m4[r1 * 16u + (u32)q];
        ACC4(u0);
        ACC4(u1);
    }
    if (e + 4 <= e1) {
        u32 r0 = srcrow[e + g];
        uint4 u0 = m4[r0 * 16u + (u32)q];
        ACC4(u0);
        e += 4;
    }
    if (g == 0) {
        // self-loop message (counted once via edge-slot 0 only)
        uint4 us = m4[(u32)c * 16u + (u32)q];
        ACC4(us);
        // tail (< 4 remaining edges)
        for (; e < e1; ++e) {
            u32 r = srcrow[e];
            uint4 u = m4[r * 16u + (u32)q];
            ACC4(u);
        }
    }
    #undef ACC4

    // reduce the 4 edge-slot groups: lanes l, l^16, l^32, l^48 hold the same quad q
    #pragma unroll
    for (int k = 0; k < 4; ++k) {
        a0[k] += __shfl_xor(a0[k], 16);
        a0[k] += __shfl_xor(a0[k], 32);
        a1[k] += __shfl_xor(a1[k], 16);
        a1[k] += __shfl_xor(a1[k], 32);
    }

    if (lane < 16) {
        float di = dinv[c];
        f32x4 o0, o1;
        o0.x = di * a0[0]; o0.y = di * a1[0]; o0.z = di * a0[1]; o0.w = di * a1[1];
        o1.x = di * a0[2]; o1.y = di * a1[2]; o1.z = di * a0[3]; o1.w = di * a1[3];
        f32x4* op = (f32x4*)(out + ((size_t)c << 7)) + (q << 1);
        __builtin_nontemporal_store(o0, op);
        __builtin_nontemporal_store(o1, op + 1);
    }
}

extern "C" void kernel_launch(void* const* d_in, const int* in_sizes, int n_in,
                              void* d_out, int out_size, void* d_ws, size_t ws_size,
                              hipStream_t stream) {
    const float* x     = (const float*)d_in[0];
    const int*   edge  = (const int*)d_in[1];   // [2][E]
    const int*   id    = (const int*)d_in[2];
    const int*   label = (const int*)d_in[3];
    const float* W     = (const float*)d_in[4];
    const float* Wid   = (const float*)d_in[5];
    float*       out   = (float*)d_out;

    const int* row = edge;
    const int* col = edge + E_EDGES;

    // ws layout:
    // msgb[N*C] bf16 | S[NB*CAP] u32 | srcrow[NB*CAP] u16 | Sr[NB*CAP] u8 |
    // s_beg[N] | s_end[N] | nodeByLabel[N] | dinv[N] f32 |
    // ZERO{ cnt[N] | labCnt[8] | labOffset[8] | colCursor[NB] | rowCursor[NB] }
    __hip_bfloat16* msgb = (__hip_bfloat16*)d_ws;
    u32* S           = (u32*)(msgb + (size_t)N_NODES * C_DIM);
    u16* srcrow      = (u16*)(S + (size_t)NB * CAP);
    u8*  Sr          = (u8*)(srcrow + (size_t)NB * CAP);
    int* s_beg       = (int*)(Sr + (size_t)NB * CAP);
    int* s_end       = s_beg + N_NODES;
    int* nodeByLabel = s_end + N_NODES;
    float* dinv      = (float*)(nodeByLabel + N_NODES);
    int* cnt         = (int*)(dinv + N_NODES);
    int* labCnt      = cnt + N_NODES;
    int* labOffset   = labCnt + 8;
    int* colCursor   = labOffset + 8;
    int* rowCursor   = colCursor + NB;

    hipMemsetAsync(cnt, 0, ((size_t)N_NODES + 16 + 2 * NB) * sizeof(int), stream);

    part_hist_kernel<<<NP + NLB, PT, 0, stream>>>(row, col, label, id,
                                                  colCursor, rowCursor, S, Sr, labCnt, cnt);
    csr_fill_kernel <<<2 * NB + NLB, PT, 0, stream>>>(S, Sr, colCursor, rowCursor,
                                                      s_beg, s_end, srcrow, dinv,
                                                      label, labCnt, labOffset, nodeByLabel);
    node_msg_kernel <<<NMB, 256, 0, stream>>>(x, cnt, label, dinv, W, Wid,
                                              nodeByLabel, msgb);
    gather_kernel   <<<N_NODES / 4, 256, 0, stream>>>(s_beg, s_end, srcrow, dinv,
                                                      (const u32*)msgb, out);
}

// Round 15
// 219.291 us; speedup vs baseline: 1.0794x; 1.0085x over previous
//
#include <hip/hip_runtime.h>
#include <hip/hip_bf16.h>

typedef unsigned int   u32;
typedef unsigned short u16;
typedef unsigned char  u8;
typedef float f32x2 __attribute__((ext_vector_type(2)));
typedef float f32x4 __attribute__((ext_vector_type(4)));

#define N_NODES 50000
#define C_DIM   128
#define E_EDGES 1600000
#define NUM_IDX 2048

#define CPB 256                    // cols per coarse bucket (key >> 8)
#define NB  196                    // ceil(N/CPB)
#define CAP 9216                   // padded capacity per bucket (mean 8192, sigma ~90)
#define CHK 8192                   // edges per chunk
#define NP  196                    // ceil(E/CHK)
#define PT  512                    // threads for partition-family kernels
#define EPT 16                     // edges per thread in partition (CHK/PT)
#define EC  18                     // bucket elems per thread in csr (CAP/PT)
#define GB  8                      // nodes per label-matmul block
#define NLB 98                     // label-stripe blocks of 512 (ceil(N/512))

// LESSONS (journal):
// r5: device-scope global atomics on MI355X are HBM-side RMW. Keep hists in LDS.
// r6: f32x4-casting per-g LDS reads in double-unrolled loops -> scratch spill.
// r7: node_msg k-major staging (xsT[k][g]) -> broadcast b128 reads.
// r8: gather one-shot is L3-random bound (149MB @ 2.7TB/s = 54us floor).
// r10: channel-split gather REGRESSED (no L2 residency vs streaming tenants).
// r12: GB=16 REGRESSED (occupancy 40->14%): node_msg latency-hiding bound.
// r13: channel pairing (2t,2t+1) REGRESSED: 16-way staging bank conflict.
// r14: 4-wave block packing REGRESSED (+5us): barrier-coupling of independent
//      groups > occupancy gain. Keep r11's 1-wave 64-thr node_msg.
//      This round: csr fine-branch register-caches its bucket (vv[18]) ->
//      single S pass (was hist-read + scatter-read).

// K_A: blocks 0..NP-1 partition edges into padded bucket regions (zero-based
// cursors: reservation adds b*CAP). Blocks NP.. do label/id histogram.
__global__ void part_hist_kernel(const int* __restrict__ row, const int* __restrict__ col,
                                 const int* __restrict__ label, const int* __restrict__ id,
                                 int* __restrict__ colCursor, int* __restrict__ rowCursor,
                                 u32* __restrict__ S, u8* __restrict__ Sr,
                                 int* __restrict__ labCnt, int* __restrict__ cnt) {
    __shared__ int hc[NB], hr[NB], bc[NB], br[NB];
    __shared__ int h8[8];
    int t = threadIdx.x;
    if (blockIdx.x >= NP) {
        // ---- label/id histogram branch (98 blocks x 512 threads) ----
        if (t < 8) h8[t] = 0;
        __syncthreads();
        int n = (blockIdx.x - NP) * PT + t;
        if (n < N_NODES) atomicAdd(&h8[label[n]], 1);
        if (n < NUM_IDX) atomicAdd(&cnt[id[n]], 1);   // blocks 0..3 cover 2048 ids
        __syncthreads();
        if (t < 8 && h8[t] > 0) atomicAdd(&labCnt[t], h8[t]);
        return;
    }
    // ---- partition branch ----
    int p = blockIdx.x;
    for (int i = t; i < NB; i += PT) { hc[i] = 0; hr[i] = 0; }
    __syncthreads();
    int e0 = p * CHK, e1 = min(e0 + CHK, E_EDGES);
    int rr[EPT], cc[EPT];
    #pragma unroll
    for (int i = 0; i < EPT; ++i) {
        int e = e0 + t + i * PT;
        if (e < e1) {
            int r = row[e], c = col[e];
            rr[i] = r; cc[i] = c;
            atomicAdd(&hc[c >> 8], 1);
            atomicAdd(&hr[r >> 8], 1);
        }
    }
    __syncthreads();
    for (int i = t; i < NB; i += PT) {
        bc[i] = (hc[i] > 0) ? (i * CAP + atomicAdd(&colCursor[i], hc[i])) : 0;
        br[i] = (hr[i] > 0) ? (i * CAP + atomicAdd(&rowCursor[i], hr[i])) : 0;
    }
    __syncthreads();
    #pragma unroll
    for (int i = 0; i < EPT; ++i) {
        int e = e0 + t + i * PT;
        if (e < e1) {
            int r = rr[i], c = cc[i];
            int pc = atomicAdd(&bc[c >> 8], 1);
            S[pc] = ((u32)r << 8) | (u32)(c & 255);
            int pr = atomicAdd(&br[r >> 8], 1);
            Sr[pr] = (u8)(r & 255);
        }
    }
}

// K_B: blocks 0..NB-1 fine-CSR; NB..2NB-1 degree/dinv; 2NB.. label_fill.
// Fine-CSR branch register-caches its bucket (one S read total, r14 change).
__global__ void csr_fill_kernel(const u32* __restrict__ S, const u8* __restrict__ Sr,
                                const int* __restrict__ colCursor, const int* __restrict__ rowCursor,
                                int* __restrict__ s_beg, int* __restrict__ s_end,
                                u16* __restrict__ srcrow, float* __restrict__ dinv,
                                const int* __restrict__ label, const int* __restrict__ labCnt,
                                int* __restrict__ labOffset, int* __restrict__ nodeByLabel) {
    __shared__ int h[CPB], cur[CPB], sc[CPB];
    __shared__ int h8[8], base8[8], c28[8];
    int t = threadIdx.x;
    if (blockIdx.x >= 2 * NB) {
        // ---- label_fill branch (98 blocks x 512 threads) ----
        if (t < 8) { h8[t] = 0; c28[t] = 0; }
        __syncthreads();
        int n = (blockIdx.x - 2 * NB) * PT + t;
        int l = 0;
        if (n < N_NODES) { l = label[n]; atomicAdd(&h8[l], 1); }
        __syncthreads();
        if (t < 8 && h8[t] > 0) {
            int lb = 0;                          // labBase[l] = prefix of labCnt
            for (int i = 0; i < t; ++i) lb += labCnt[i];
            base8[t] = lb + atomicAdd(&labOffset[t], h8[t]);
        }
        __syncthreads();
        if (n < N_NODES) {
            int pos = base8[l] + atomicAdd(&c28[l], 1);
            nodeByLabel[pos] = n;
        }
        return;
    }
    if (blockIdx.x >= NB) {
        // ---- degree branch: LDS histogram of Sr bucket -> dinv ----
        int b = blockIdx.x - NB;
        if (t < CPB) h[t] = 0;
        __syncthreads();
        int e0 = b * CAP, e1 = b * CAP + rowCursor[b];
        for (int e = e0 + t; e < e1; e += PT) atomicAdd(&h[Sr[e]], 1);
        __syncthreads();
        if (t < CPB) {
            int n = b * CPB + t;
            if (n < N_NODES) dinv[n] = rsqrtf((float)(h[t] + 1));
        }
        return;
    }
    // ---- fine-CSR branch (single S pass via register cache) ----
    int b = blockIdx.x;
    if (t < CPB) h[t] = 0;
    __syncthreads();
    int e0 = b * CAP, e1 = b * CAP + colCursor[b];
    u32 vv[EC];                              // packed values < 2^24, so ~0u is a safe sentinel
    #pragma unroll
    for (int i = 0; i < EC; ++i) {
        int e = e0 + t + i * PT;
        vv[i] = (e < e1) ? S[e] : 0xffffffffu;
        if (vv[i] != 0xffffffffu) atomicAdd(&h[vv[i] & 255u], 1);
    }
    __syncthreads();
    if (t < CPB) sc[t] = h[t];
    __syncthreads();
    for (int off = 1; off < CPB; off <<= 1) {
        int v = 0, a = 0;
        if (t < CPB) { v = sc[t]; a = (t >= off) ? sc[t - off] : 0; }
        __syncthreads();
        if (t < CPB) sc[t] = v + a;
        __syncthreads();
    }
    if (t < CPB) {
        int base = (t == 0) ? 0 : sc[t - 1];
        int gcol = b * CPB + t;
        if (gcol < N_NODES) {
            s_beg[gcol] = e0 + base;
            s_end[gcol] = e0 + base + h[t];
        }
        cur[t] = base;
    }
    __syncthreads();
    #pragma unroll
    for (int i = 0; i < EC; ++i) {
        if (vv[i] != 0xffffffffu) {
            int pos = atomicAdd(&cur[vv[i] & 255u], 1);
            srcrow[e0 + pos] = (u16)(vv[i] >> 8);
        }
    }
}

// K6: label-grouped node transform -> bf16 messages (exact r11 body —
// 1 wave x 64 thr, channels (t, t+64), GB=8; proven best).
__global__ void node_msg_kernel(const float* __restrict__ x,
                                const int* __restrict__ cnt,
                                const int* __restrict__ label,
                                const float* __restrict__ dinv,
                                const float* __restrict__ W,
                                const float* __restrict__ Wid,
                                const int* __restrict__ nodeByLabel,
                                __hip_bfloat16* __restrict__ msgb) {
    __shared__ float xsT[C_DIM][GB];       // [k][g], 4 KB
    __shared__ int nid[GB], lab[GB], cc[GB];
    int t = threadIdx.x;                   // 0..63
    int t2 = t + 64;
    if (t < GB) {
        int n = nodeByLabel[blockIdx.x * GB + t];
        nid[t] = n; lab[t] = label[n]; cc[t] = cnt[n];
    }
    __syncthreads();
    #pragma unroll
    for (int g = 0; g < GB; ++g) {
        xsT[t][g]  = __builtin_nontemporal_load(x + (size_t)nid[g] * C_DIM + t);
        xsT[t2][g] = __builtin_nontemporal_load(x + (size_t)nid[g] * C_DIM + t2);
    }
    __syncthreads();
    for (int g = 0; g < GB; ++g) {          // ego update (~4% of nodes)
        int c = cc[g];
        if (c > 0) {
            float a0 = 0.f, a1 = 0.f;
            #pragma unroll 8
            for (int k = 0; k < C_DIM; ++k) {
                float xv = xsT[k][g];
                a0 += xv * W[k * C_DIM + t];
                a1 += xv * W[k * C_DIM + t2];
            }
            __syncthreads();
            xsT[t][g]  += (float)c * a0;
            xsT[t2][g] += (float)c * a1;
            __syncthreads();
        }
    }
    float acc0[GB], acc1[GB];
    #pragma unroll
    for (int g = 0; g < GB; ++g) { acc0[g] = xsT[t][g]; acc1[g] = xsT[t2][g]; }
    if (lab[0] == lab[GB - 1]) {
        int L = lab[0];
        if (L > 0) {
            const float* Wl = Wid + (size_t)(L - 1) * C_DIM * C_DIM;
            for (int k = 0; k < C_DIM; ++k) {
                float w0 = Wl[k * C_DIM + t];
                float w1 = Wl[k * C_DIM + t2];
                f32x4 xa = *(const f32x4*)&xsT[k][0];    // broadcast b128
                f32x4 xb = *(const f32x4*)&xsT[k][4];    // broadcast b128
                acc0[0] += xa.x * w0; acc0[1] += xa.y * w0;
                acc0[2] += xa.z * w0; acc0[3] += xa.w * w0;
                acc0[4] += xb.x * w0; acc0[5] += xb.y * w0;
                acc0[6] += xb.z * w0; acc0[7] += xb.w * w0;
                acc1[0] += xa.x * w1; acc1[1] += xa.y * w1;
                acc1[2] += xa.z * w1; acc1[3] += xa.w * w1;
                acc1[4] += xb.x * w1; acc1[5] += xb.y * w1;
                acc1[6] += xb.z * w1; acc1[7] += xb.w * w1;
            }
        }
    } else {
        for (int g = 0; g < GB; ++g) {
            int L = lab[g];
            if (L > 0) {
                const float* Wl = Wid + (size_t)(L - 1) * C_DIM * C_DIM;
                float a0 = 0.f, a1 = 0.f;
                #pragma unroll 8
                for (int k = 0; k < C_DIM; ++k) {
                    float xv = xsT[k][g];
                    a0 += xv * Wl[k * C_DIM + t];
                    a1 += xv * Wl[k * C_DIM + t2];
                }
                acc0[g] += a0; acc1[g] += a1;
            }
        }
    }
    #pragma unroll
    for (int g = 0; g < GB; ++g) {
        int n = nid[g];
        float di = dinv[n];
        msgb[(size_t)n * C_DIM + t]  = __float2bfloat16(di * acc0[g]);
        msgb[(size_t)n * C_DIM + t2] = __float2bfloat16(di * acc1[g]);
    }
}

// K7: gather + finalize (single-pass, r8 proven form). One wave per dest node;
// 4 edges in flight per wave. lane = (g,q): g = edge slot, q = channel quad.
__global__ void gather_kernel(const int* __restrict__ s_beg, const int* __restrict__ s_end,
                              const u16* __restrict__ srcrow,
                              const float* __restrict__ dinv,
                              const u32* __restrict__ m32,   // bf16x2-packed msg
                              float* __restrict__ out) {
    int wid  = threadIdx.x >> 6;
    int lane = threadIdx.x & 63;
    int g = lane >> 4;
    int q = lane & 15;
    int c = blockIdx.x * 4 + wid;
    int e0 = s_beg[c], e1 = s_end[c];
    const uint4* m4 = (const uint4*)m32;   // one node = 16 uint4

    float a0[4], a1[4];
    #pragma unroll
    for (int k = 0; k < 4; ++k) { a0[k] = 0.f; a1[k] = 0.f; }

    #define ACC4(U)                                                          \
        a0[0] += __uint_as_float((U).x << 16); a1[0] += __uint_as_float((U).x & 0xffff0000u); \
        a0[1] += __uint_as_float((U).y << 16); a1[1] += __uint_as_float((U).y & 0xffff0000u); \
        a0[2] += __uint_as_float((U).z << 16); a1[2] += __uint_as_float((U).z & 0xffff0000u); \
        a0[3] += __uint_as_float((U).w << 16); a1[3] += __uint_as_float((U).w & 0xffff0000u);

    int e = e0;
    for (; e + 8 <= e1; e += 8) {
        u32 r0 = srcrow[e + g];
        u32 r1 = srcrow[e + 4 + g];
        uint4 u0 = m4[r0 * 16u + (u32)q];
        uint4 u1 = m4[r1 * 16u + (u32)q];
        ACC4(u0);
        ACC4(u1);
    }
    if (e + 4 <= e1) {
        u32 r0 = srcrow[e + g];
        uint4 u0 = m4[r0 * 16u + (u32)q];
        ACC4(u0);
        e += 4;
    }
    if (g == 0) {
        // self-loop message (counted once via edge-slot 0 only)
        uint4 us = m4[(u32)c * 16u + (u32)q];
        ACC4(us);
        // tail (< 4 remaining edges)
        for (; e < e1; ++e) {
            u32 r = srcrow[e];
            uint4 u = m4[r * 16u + (u32)q];
            ACC4(u);
        }
    }
    #undef ACC4

    // reduce the 4 edge-slot groups: lanes l, l^16, l^32, l^48 hold the same quad q
    #pragma unroll
    for (int k = 0; k < 4; ++k) {
        a0[k] += __shfl_xor(a0[k], 16);
        a0[k] += __shfl_xor(a0[k], 32);
        a1[k] += __shfl_xor(a1[k], 16);
        a1[k] += __shfl_xor(a1[k], 32);
    }

    if (lane < 16) {
        float di = dinv[c];
        f32x4 o0, o1;
        o0.x = di * a0[0]; o0.y = di * a1[0]; o0.z = di * a0[1]; o0.w = di * a1[1];
        o1.x = di * a0[2]; o1.y = di * a1[2]; o1.z = di * a0[3]; o1.w = di * a1[3];
        f32x4* op = (f32x4*)(out + ((size_t)c << 7)) + (q << 1);
        __builtin_nontemporal_store(o0, op);
        __builtin_nontemporal_store(o1, op + 1);
    }
}

extern "C" void kernel_launch(void* const* d_in, const int* in_sizes, int n_in,
                              void* d_out, int out_size, void* d_ws, size_t ws_size,
                              hipStream_t stream) {
    const float* x     = (const float*)d_in[0];
    const int*   edge  = (const int*)d_in[1];   // [2][E]
    const int*   id    = (const int*)d_in[2];
    const int*   label = (const int*)d_in[3];
    const float* W     = (const float*)d_in[4];
    const float* Wid   = (const float*)d_in[5];
    float*       out   = (float*)d_out;

    const int* row = edge;
    const int* col = edge + E_EDGES;

    // ws layout:
    // msgb[N*C] bf16 | S[NB*CAP] u32 | srcrow[NB*CAP] u16 | Sr[NB*CAP] u8 |
    // s_beg[N] | s_end[N] | nodeByLabel[N] | dinv[N] f32 |
    // ZERO{ cnt[N] | labCnt[8] | labOffset[8] | colCursor[NB] | rowCursor[NB] }
    __hip_bfloat16* msgb = (__hip_bfloat16*)d_ws;
    u32* S           = (u32*)(msgb + (size_t)N_NODES * C_DIM);
    u16* srcrow      = (u16*)(S + (size_t)NB * CAP);
    u8*  Sr          = (u8*)(srcrow + (size_t)NB * CAP);
    int* s_beg       = (int*)(Sr + (size_t)NB * CAP);
    int* s_end       = s_beg + N_NODES;
    int* nodeByLabel = s_end + N_NODES;
    float* dinv      = (float*)(nodeByLabel + N_NODES);
    int* cnt         = (int*)(dinv + N_NODES);
    int* labCnt      = cnt + N_NODES;
    int* labOffset   = labCnt + 8;
    int* colCursor   = labOffset + 8;
    int* rowCursor   = colCursor + NB;

    hipMemsetAsync(cnt, 0, ((size_t)N_NODES + 16 + 2 * NB) * sizeof(int), stream);

    part_hist_kernel<<<NP + NLB, PT, 0, stream>>>(row, col, label, id,
                                                  colCursor, rowCursor, S, Sr, labCnt, cnt);
    csr_fill_kernel <<<2 * NB + NLB, PT, 0, stream>>>(S, Sr, colCursor, rowCursor,
                                                      s_beg, s_end, srcrow, dinv,
                                                      label, labCnt, labOffset, nodeByLabel);
    node_msg_kernel <<<N_NODES / GB, 64, 0, stream>>>(x, cnt, label, dinv, W, Wid,
                                                      nodeByLabel, msgb);
    gather_kernel   <<<N_NODES / 4, 256, 0, stream>>>(s_beg, s_end, srcrow, dinv,
                                                      (const u32*)msgb, out);
}

// Round 16
// 218.515 us; speedup vs baseline: 1.0832x; 1.0035x over previous
//
#include <hip/hip_runtime.h>
#include <hip/hip_bf16.h>

typedef unsigned int   u32;
typedef unsigned short u16;
typedef unsigned char  u8;
typedef float f32x2 __attribute__((ext_vector_type(2)));
typedef float f32x4 __attribute__((ext_vector_type(4)));

#define N_NODES 50000
#define C_DIM   128
#define E_EDGES 1600000
#define NUM_IDX 2048

#define CPB 256                    // cols per coarse bucket (key >> 8)
#define NB  196                    // ceil(N/CPB)
#define CAP 9216                   // padded capacity per bucket (mean 8192, sigma ~90)
#define CHK 8192                   // edges per chunk
#define NP  196                    // ceil(E/CHK)
#define PT  512                    // threads for partition-family kernels
#define EPT 16                     // edges per thread in partition (CHK/PT)
#define EC  18                     // bucket elems per thread in csr (CAP/PT)
#define GB  8                      // nodes per label-matmul block
#define NLB 98                     // label-stripe blocks of 512 (ceil(N/512))

// LESSONS (journal):
// r5: device-scope global atomics on MI355X are HBM-side RMW. Keep hists in LDS.
// r6: f32x4-casting per-g LDS reads in double-unrolled loops -> scratch spill.
// r7: node_msg k-major staging (xsT[k][g]) -> broadcast b128 reads.
// r8: gather one-shot is L3-random bound (149MB @ 2.7TB/s = 54us floor).
// r10: channel-split gather REGRESSED (no L2 residency vs streaming tenants).
// r12: GB=16 REGRESSED (occupancy 40->14%): node_msg latency-hiding bound.
// r13: channel pairing (2t,2t+1) REGRESSED: 16-way staging bank conflict.
// r14: 4-wave packing REGRESSED: barrier-coupling > occupancy gain.
// r15: csr single-S-pass register cache: neutral (within noise).
//      This round: RANK TRICK — pass-1 hist atomic's return value IS the
//      within-block rank; scatter becomes base[bucket]+rank with ZERO atomics.
//      part_hist 4->2 LDS atomics/edge; csr fine branch 2->1.

// K_A: blocks 0..NP-1 partition edges into padded bucket regions (zero-based
// cursors: reservation adds b*CAP). Blocks NP.. do label/id histogram.
__global__ void part_hist_kernel(const int* __restrict__ row, const int* __restrict__ col,
                                 const int* __restrict__ label, const int* __restrict__ id,
                                 int* __restrict__ colCursor, int* __restrict__ rowCursor,
                                 u32* __restrict__ S, u8* __restrict__ Sr,
                                 int* __restrict__ labCnt, int* __restrict__ cnt) {
    __shared__ int hc[NB], hr[NB], bc[NB], br[NB];
    __shared__ int h8[8];
    int t = threadIdx.x;
    if (blockIdx.x >= NP) {
        // ---- label/id histogram branch (98 blocks x 512 threads) ----
        if (t < 8) h8[t] = 0;
        __syncthreads();
        int n = (blockIdx.x - NP) * PT + t;
        if (n < N_NODES) atomicAdd(&h8[label[n]], 1);
        if (n < NUM_IDX) atomicAdd(&cnt[id[n]], 1);   // blocks 0..3 cover 2048 ids
        __syncthreads();
        if (t < 8 && h8[t] > 0) atomicAdd(&labCnt[t], h8[t]);
        return;
    }
    // ---- partition branch: pass1 hist captures per-edge rank; scatter is
    // atomic-free (r15 rank trick) ----
    int p = blockIdx.x;
    for (int i = t; i < NB; i += PT) { hc[i] = 0; hr[i] = 0; }
    __syncthreads();
    int e0 = p * CHK, e1 = min(e0 + CHK, E_EDGES);
    int rr[EPT], cc[EPT], rkc[EPT], rkr[EPT];
    #pragma unroll
    for (int i = 0; i < EPT; ++i) {
        int e = e0 + t + i * PT;
        if (e < e1) {
            int r = row[e], c = col[e];
            rr[i] = r; cc[i] = c;
            rkc[i] = atomicAdd(&hc[c >> 8], 1);   // rank within block's bucket
            rkr[i] = atomicAdd(&hr[r >> 8], 1);
        }
    }
    __syncthreads();
    for (int i = t; i < NB; i += PT) {
        bc[i] = (hc[i] > 0) ? (i * CAP + atomicAdd(&colCursor[i], hc[i])) : 0;
        br[i] = (hr[i] > 0) ? (i * CAP + atomicAdd(&rowCursor[i], hr[i])) : 0;
    }
    __syncthreads();
    #pragma unroll
    for (int i = 0; i < EPT; ++i) {
        int e = e0 + t + i * PT;
        if (e < e1) {
            int r = rr[i], c = cc[i];
            S[bc[c >> 8] + rkc[i]] = ((u32)r << 8) | (u32)(c & 255);
            Sr[br[r >> 8] + rkr[i]] = (u8)(r & 255);
        }
    }
}

// K_B: blocks 0..NB-1 fine-CSR; NB..2NB-1 degree/dinv; 2NB.. label_fill.
// Fine-CSR: single S pass + rank trick (scatter has zero atomics).
__global__ void csr_fill_kernel(const u32* __restrict__ S, const u8* __restrict__ Sr,
                                const int* __restrict__ colCursor, const int* __restrict__ rowCursor,
                                int* __restrict__ s_beg, int* __restrict__ s_end,
                                u16* __restrict__ srcrow, float* __restrict__ dinv,
                                const int* __restrict__ label, const int* __restrict__ labCnt,
                                int* __restrict__ labOffset, int* __restrict__ nodeByLabel) {
    __shared__ int h[CPB], cur[CPB], sc[CPB];
    __shared__ int h8[8], base8[8], c28[8];
    int t = threadIdx.x;
    if (blockIdx.x >= 2 * NB) {
        // ---- label_fill branch (98 blocks x 512 threads) ----
        if (t < 8) { h8[t] = 0; c28[t] = 0; }
        __syncthreads();
        int n = (blockIdx.x - 2 * NB) * PT + t;
        int l = 0;
        if (n < N_NODES) { l = label[n]; atomicAdd(&h8[l], 1); }
        __syncthreads();
        if (t < 8 && h8[t] > 0) {
            int lb = 0;                          // labBase[l] = prefix of labCnt
            for (int i = 0; i < t; ++i) lb += labCnt[i];
            base8[t] = lb + atomicAdd(&labOffset[t], h8[t]);
        }
        __syncthreads();
        if (n < N_NODES) {
            int pos = base8[l] + atomicAdd(&c28[l], 1);
            nodeByLabel[pos] = n;
        }
        return;
    }
    if (blockIdx.x >= NB) {
        // ---- degree branch: LDS histogram of Sr bucket -> dinv ----
        int b = blockIdx.x - NB;
        if (t < CPB) h[t] = 0;
        __syncthreads();
        int e0 = b * CAP, e1 = b * CAP + rowCursor[b];
        for (int e = e0 + t; e < e1; e += PT) atomicAdd(&h[Sr[e]], 1);
        __syncthreads();
        if (t < CPB) {
            int n = b * CPB + t;
            if (n < N_NODES) dinv[n] = rsqrtf((float)(h[t] + 1));
        }
        return;
    }
    // ---- fine-CSR branch (single S pass, rank-trick scatter) ----
    int b = blockIdx.x;
    if (t < CPB) h[t] = 0;
    __syncthreads();
    int e0 = b * CAP, e1 = b * CAP + colCursor[b];
    u32 vv[EC];                              // packed values < 2^24, ~0u sentinel
    int rk[EC];
    #pragma unroll
    for (int i = 0; i < EC; ++i) {
        int e = e0 + t + i * PT;
        if (e < e1) {
            vv[i] = S[e];
            rk[i] = atomicAdd(&h[vv[i] & 255u], 1);   // rank within fine col
        } else {
            vv[i] = 0xffffffffu;
        }
    }
    __syncthreads();
    if (t < CPB) sc[t] = h[t];
    __syncthreads();
    for (int off = 1; off < CPB; off <<= 1) {
        int v = 0, a = 0;
        if (t < CPB) { v = sc[t]; a = (t >= off) ? sc[t - off] : 0; }
        __syncthreads();
        if (t < CPB) sc[t] = v + a;
        __syncthreads();
    }
    if (t < CPB) {
        int base = (t == 0) ? 0 : sc[t - 1];
        int gcol = b * CPB + t;
        if (gcol < N_NODES) {
            s_beg[gcol] = e0 + base;
            s_end[gcol] = e0 + base + h[t];
        }
        cur[t] = base;                       // per-fine-col base (read-only below)
    }
    __syncthreads();
    #pragma unroll
    for (int i = 0; i < EC; ++i) {
        if (vv[i] != 0xffffffffu) {
            srcrow[e0 + cur[vv[i] & 255u] + rk[i]] = (u16)(vv[i] >> 8);
        }
    }
}

// K6: label-grouped node transform -> bf16 messages (exact r11 body —
// 1 wave x 64 thr, channels (t, t+64), GB=8; proven best).
__global__ void node_msg_kernel(const float* __restrict__ x,
                                const int* __restrict__ cnt,
                                const int* __restrict__ label,
                                const float* __restrict__ dinv,
                                const float* __restrict__ W,
                                const float* __restrict__ Wid,
                                const int* __restrict__ nodeByLabel,
                                __hip_bfloat16* __restrict__ msgb) {
    __shared__ float xsT[C_DIM][GB];       // [k][g], 4 KB
    __shared__ int nid[GB], lab[GB], cc[GB];
    int t = threadIdx.x;                   // 0..63
    int t2 = t + 64;
    if (t < GB) {
        int n = nodeByLabel[blockIdx.x * GB + t];
        nid[t] = n; lab[t] = label[n]; cc[t] = cnt[n];
    }
    __syncthreads();
    #pragma unroll
    for (int g = 0; g < GB; ++g) {
        xsT[t][g]  = __builtin_nontemporal_load(x + (size_t)nid[g] * C_DIM + t);
        xsT[t2][g] = __builtin_nontemporal_load(x + (size_t)nid[g] * C_DIM + t2);
    }
    __syncthreads();
    for (int g = 0; g < GB; ++g) {          // ego update (~4% of nodes)
        int c = cc[g];
        if (c > 0) {
            float a0 = 0.f, a1 = 0.f;
            #pragma unroll 8
            for (int k = 0; k < C_DIM; ++k) {
                float xv = xsT[k][g];
                a0 += xv * W[k * C_DIM + t];
                a1 += xv * W[k * C_DIM + t2];
            }
            __syncthreads();
            xsT[t][g]  += (float)c * a0;
            xsT[t2][g] += (float)c * a1;
            __syncthreads();
        }
    }
    float acc0[GB], acc1[GB];
    #pragma unroll
    for (int g = 0; g < GB; ++g) { acc0[g] = xsT[t][g]; acc1[g] = xsT[t2][g]; }
    if (lab[0] == lab[GB - 1]) {
        int L = lab[0];
        if (L > 0) {
            const float* Wl = Wid + (size_t)(L - 1) * C_DIM * C_DIM;
            for (int k = 0; k < C_DIM; ++k) {
                float w0 = Wl[k * C_DIM + t];
                float w1 = Wl[k * C_DIM + t2];
                f32x4 xa = *(const f32x4*)&xsT[k][0];    // broadcast b128
                f32x4 xb = *(const f32x4*)&xsT[k][4];    // broadcast b128
                acc0[0] += xa.x * w0; acc0[1] += xa.y * w0;
                acc0[2] += xa.z * w0; acc0[3] += xa.w * w0;
                acc0[4] += xb.x * w0; acc0[5] += xb.y * w0;
                acc0[6] += xb.z * w0; acc0[7] += xb.w * w0;
                acc1[0] += xa.x * w1; acc1[1] += xa.y * w1;
                acc1[2] += xa.z * w1; acc1[3] += xa.w * w1;
                acc1[4] += xb.x * w1; acc1[5] += xb.y * w1;
                acc1[6] += xb.z * w1; acc1[7] += xb.w * w1;
            }
        }
    } else {
        for (int g = 0; g < GB; ++g) {
            int L = lab[g];
            if (L > 0) {
                const float* Wl = Wid + (size_t)(L - 1) * C_DIM * C_DIM;
                float a0 = 0.f, a1 = 0.f;
                #pragma unroll 8
                for (int k = 0; k < C_DIM; ++k) {
                    float xv = xsT[k][g];
                    a0 += xv * Wl[k * C_DIM + t];
                    a1 += xv * Wl[k * C_DIM + t2];
                }
                acc0[g] += a0; acc1[g] += a1;
            }
        }
    }
    #pragma unroll
    for (int g = 0; g < GB; ++g) {
        int n = nid[g];
        float di = dinv[n];
        msgb[(size_t)n * C_DIM + t]  = __float2bfloat16(di * acc0[g]);
        msgb[(size_t)n * C_DIM + t2] = __float2bfloat16(di * acc1[g]);
    }
}

// K7: gather + finalize (single-pass, r8 proven form). One wave per dest node;
// 4 edges in flight per wave. lane = (g,q): g = edge slot, q = channel quad.
__global__ void gather_kernel(const int* __restrict__ s_beg, const int* __restrict__ s_end,
                              const u16* __restrict__ srcrow,
                              const float* __restrict__ dinv,
                              const u32* __restrict__ m32,   // bf16x2-packed msg
                              float* __restrict__ out) {
    int wid  = threadIdx.x >> 6;
    int lane = threadIdx.x & 63;
    int g = lane >> 4;
    int q = lane & 15;
    int c = blockIdx.x * 4 + wid;
    int e0 = s_beg[c], e1 = s_end[c];
    const uint4* m4 = (const uint4*)m32;   // one node = 16 uint4

    float a0[4], a1[4];
    #pragma unroll
    for (int k = 0; k < 4; ++k) { a0[k] = 0.f; a1[k] = 0.f; }

    #define ACC4(U)                                                          \
        a0[0] += __uint_as_float((U).x << 16); a1[0] += __uint_as_float((U).x & 0xffff0000u); \
        a0[1] += __uint_as_float((U).y << 16); a1[1] += __uint_as_float((U).y & 0xffff0000u); \
        a0[2] += __uint_as_float((U).z << 16); a1[2] += __uint_as_float((U).z & 0xffff0000u); \
        a0[3] += __uint_as_float((U).w << 16); a1[3] += __uint_as_float((U).w & 0xffff0000u);

    int e = e0;
    for (; e + 8 <= e1; e += 8) {
        u32 r0 = srcrow[e + g];
        u32 r1 = srcrow[e + 4 + g];
        uint4 u0 = m4[r0 * 16u + (u32)q];
        uint4 u1 = m4[r1 * 16u + (u32)q];
        ACC4(u0);
        ACC4(u1);
    }
    if (e + 4 <= e1) {
        u32 r0 = srcrow[e + g];
        uint4 u0 = m4[r0 * 16u + (u32)q];
        ACC4(u0);
        e += 4;
    }
    if (g == 0) {
        // self-loop message (counted once via edge-slot 0 only)
        uint4 us = m4[(u32)c * 16u + (u32)q];
        ACC4(us);
        // tail (< 4 remaining edges)
        for (; e < e1; ++e) {
            u32 r = srcrow[e];
            uint4 u = m4[r * 16u + (u32)q];
            ACC4(u);
        }
    }
    #undef ACC4

    // reduce the 4 edge-slot groups: lanes l, l^16, l^32, l^48 hold the same quad q
    #pragma unroll
    for (int k = 0; k < 4; ++k) {
        a0[k] += __shfl_xor(a0[k], 16);
        a0[k] += __shfl_xor(a0[k], 32);
        a1[k] += __shfl_xor(a1[k], 16);
        a1[k] += __shfl_xor(a1[k], 32);
    }

    if (lane < 16) {
        float di = dinv[c];
        f32x4 o0, o1;
        o0.x = di * a0[0]; o0.y = di * a1[0]; o0.z = di * a0[1]; o0.w = di * a1[1];
        o1.x = di * a0[2]; o1.y = di * a1[2]; o1.z = di * a0[3]; o1.w = di * a1[3];
        f32x4* op = (f32x4*)(out + ((size_t)c << 7)) + (q << 1);
        __builtin_nontemporal_store(o0, op);
        __builtin_nontemporal_store(o1, op + 1);
    }
}

extern "C" void kernel_launch(void* const* d_in, const int* in_sizes, int n_in,
                              void* d_out, int out_size, void* d_ws, size_t ws_size,
                              hipStream_t stream) {
    const float* x     = (const float*)d_in[0];
    const int*   edge  = (const int*)d_in[1];   // [2][E]
    const int*   id    = (const int*)d_in[2];
    const int*   label = (const int*)d_in[3];
    const float* W     = (const float*)d_in[4];
    const float* Wid   = (const float*)d_in[5];
    float*       out   = (float*)d_out;

    const int* row = edge;
    const int* col = edge + E_EDGES;

    // ws layout:
    // msgb[N*C] bf16 | S[NB*CAP] u32 | srcrow[NB*CAP] u16 | Sr[NB*CAP] u8 |
    // s_beg[N] | s_end[N] | nodeByLabel[N] | dinv[N] f32 |
    // ZERO{ cnt[N] | labCnt[8] | labOffset[8] | colCursor[NB] | rowCursor[NB] }
    __hip_bfloat16* msgb = (__hip_bfloat16*)d_ws;
    u32* S           = (u32*)(msgb + (size_t)N_NODES * C_DIM);
    u16* srcrow      = (u16*)(S + (size_t)NB * CAP);
    u8*  Sr          = (u8*)(srcrow + (size_t)NB * CAP);
    int* s_beg       = (int*)(Sr + (size_t)NB * CAP);
    int* s_end       = s_beg + N_NODES;
    int* nodeByLabel = s_end + N_NODES;
    float* dinv      = (float*)(nodeByLabel + N_NODES);
    int* cnt         = (int*)(dinv + N_NODES);
    int* labCnt      = cnt + N_NODES;
    int* labOffset   = labCnt + 8;
    int* colCursor   = labOffset + 8;
    int* rowCursor   = colCursor + NB;

    hipMemsetAsync(cnt, 0, ((size_t)N_NODES + 16 + 2 * NB) * sizeof(int), stream);

    part_hist_kernel<<<NP + NLB, PT, 0, stream>>>(row, col, label, id,
                                                  colCursor, rowCursor, S, Sr, labCnt, cnt);
    csr_fill_kernel <<<2 * NB + NLB, PT, 0, stream>>>(S, Sr, colCursor, rowCursor,
                                                      s_beg, s_end, srcrow, dinv,
                                                      label, labCnt, labOffset, nodeByLabel);
    node_msg_kernel <<<N_NODES / GB, 64, 0, stream>>>(x, cnt, label, dinv, W, Wid,
                                                      nodeByLabel, msgb);
    gather_kernel   <<<N_NODES / 4, 256, 0, stream>>>(s_beg, s_end, srcrow, dinv,
                                                      (const u32*)msgb, out);
}